// Round 2
// baseline (294.943 us; speedup 1.0000x reference)
//
#include <hip/hip_runtime.h>
#include <stdint.h>

#define N_EXPERTS 8
#define IN_DIM    1024
#define OUT_DIM   1024
#define N_TOKENS  16384
#define S_SLOTS   (N_TOKENS * 2)
#define BM 128
#define BN 128
#define BK 64                     // K-cols per tile step (fp32 source)
#define MAX_TILES 264             // sum ceil(cnt_e/128) <= 256 + 8
#define NGROUPS   (OUT_DIM / BN)  // 8
#define NXCD      8
#define CPX       (MAX_TILES / NXCD)   // 33, exact (264 % 8 == 0 -> bijective)

typedef unsigned short u16;
using short8 = __attribute__((ext_vector_type(8))) short;
using f32x4  = __attribute__((ext_vector_type(4))) float;

__device__ __forceinline__ u16 f2bf(float f) {
  uint32_t x = __builtin_bit_cast(uint32_t, f);
  uint32_t r = x + 0x7fffu + ((x >> 16) & 1u);   // RTNE
  return (u16)(r >> 16);
}
__device__ __forceinline__ float bf2f(u16 u) {
  uint32_t x = ((uint32_t)u) << 16;
  return __builtin_bit_cast(float, x);
}
// hardware RTNE convert; pairs of these fold into v_cvt_pk_bf16_f32
__device__ __forceinline__ u16 cvt1(float f) {
  return __builtin_bit_cast(u16, (__bf16)f);
}

// ---------------------------------------------------------------------------
// Shared tile derivation (slots sorted by expert; <=264 M-tiles)
// ---------------------------------------------------------------------------
__device__ __forceinline__ bool derive_tile(const int* eoff_raw, bool is64,
                                            int bx, int& expert, int& rs, int& re) {
  int rem = bx, prev = 0;
  expert = -1;
  for (int e = 0; e < N_EXPERTS; ++e) {
    int end = is64 ? eoff_raw[2 * e] : eoff_raw[e];
    int cnt = end - prev;
    int nt  = (cnt + BM - 1) / BM;
    if (expert < 0) {
      if (rem < nt) {
        expert = e;
        rs = prev + rem * BM;
        re = (rs + BM < end) ? (rs + BM) : end;
      } else {
        rem -= nt;
      }
    }
    prev = end;
  }
  return expert >= 0;
}

// ---------------------------------------------------------------------------
// Node 1 (tiny): zero the straddle-pair token rows (odd tile starts) so the
// GEMM can atomicAdd the two edge contributions from different blocks.
// ---------------------------------------------------------------------------
__global__ __launch_bounds__(256) void zero_straddle(
    const int* __restrict__ eoff_raw, float* __restrict__ out) {
  const bool is64 = (eoff_raw[7] != S_SLOTS);
  int expert, rs, re;
  if (!derive_tile(eoff_raw, is64, blockIdx.x, expert, rs, re)) return;
  if (rs & 1) {
    f32x4 z = (f32x4){0.f, 0.f, 0.f, 0.f};
    *(f32x4*)(out + (size_t)(rs >> 1) * OUT_DIM + threadIdx.x * 4) = z;
  }
}

// ---------------------------------------------------------------------------
// Node 2: fused grouped GEMM.  Reads fp32 X/W directly, converts to bf16 in
// registers while staging to swizzled LDS (no separate convert pass, no bf16
// workspace traffic).  BK=64, XOR-swizzled LDS (both write & read sides) so
// the ds_read_b128 fragment loads are bank-conflict-free.
// XCD-aware bijective tile swizzle: 33 consecutive M-tiles (which share the
// same expert W-panel for a given blockIdx.y) land on one XCD's L2.
// Epilogue: proven repack + gate-combine pairs + atomicAdd edges.
// ---------------------------------------------------------------------------
__global__ __launch_bounds__(256, 2) void moe_gemm_fused(
    const float* __restrict__ X,        // [N_TOKENS, IN_DIM] fp32
    const float* __restrict__ W,        // [E, OUT_DIM, IN_DIM] fp32
    const float* __restrict__ gates,    // [S] fp32
    const int*   __restrict__ kptr,
    const int*   __restrict__ ssi_raw,  // int32 or int64
    const int*   __restrict__ eoff_raw, // int32 or int64
    float*       __restrict__ out)      // [N_TOKENS, OUT_DIM] fp32
{
  __shared__ __align__(16) u16 smem[BM * BK + BN * BK];   // 32 KB
  u16* As = smem;             // [128][64] u16, XOR-swizzled in 16B chunks
  u16* Bs = smem + BM * BK;

  const bool is64 = (eoff_raw[7] != S_SLOTS);
  // XCD-aware bijective swizzle (264 % 8 == 0; blockIdx.y doesn't shift the
  // phase since 264*by is a multiple of 8)
  const int tile = (blockIdx.x % NXCD) * CPX + blockIdx.x / NXCD;
  int expert, rs, re;
  if (!derive_tile(eoff_raw, is64, tile, expert, rs, re)) return;

  const int n0   = blockIdx.y * BN;
  const int kdiv = kptr[0];
  const int t    = threadIdx.x;

  // --- staging assignment: bf16 tile = 128 rows x 8 chunks of 16B.
  // chunk q = t + 256*i (i=0..3): row = q>>3, c = q&7.  Each chunk is 8 bf16
  // <- 8 fp32 (two f32x4 global loads).  Swizzle: chunk c' = c ^ (row&7).
  const float* arow[4];
  const float* brow[4];
  int lofs[4];
#pragma unroll
  for (int i = 0; i < 4; ++i) {
    int q = t + 256 * i;
    int row = q >> 3, c = q & 7;
    int g = rs + row; if (g >= re) g = re - 1;
    int sv  = is64 ? ssi_raw[2 * g] : ssi_raw[g];
    int tok = sv / kdiv;
    arow[i] = X + (size_t)tok * IN_DIM + c * 8;
    brow[i] = W + ((size_t)expert * OUT_DIM + n0 + row) * IN_DIM + c * 8;
    lofs[i] = row * BK + ((c ^ (row & 7)) << 3);     // u16 index
  }

  f32x4 acc[4][4];
#pragma unroll
  for (int i = 0; i < 4; ++i)
#pragma unroll
    for (int j = 0; j < 4; ++j)
      acc[i][j] = (f32x4){0.f, 0.f, 0.f, 0.f};

  const int wave = t >> 6;
  const int lane = t & 63;
  const int wm = (wave >> 1) * 64;
  const int wn = (wave & 1) * 64;
  const int lr = lane & 15;
  const int hk = lane >> 4;          // k-chunk selector within K=32 block

  for (int k0 = 0; k0 < IN_DIM; k0 += BK) {
    // -- load fp32 + convert to bf16 in regs (overlaps other waves' MFMA) --
    short8 sa[4], sb[4];
#pragma unroll
    for (int i = 0; i < 4; ++i) {
      const f32x4* pa = (const f32x4*)(arow[i] + k0);
      const f32x4* pb = (const f32x4*)(brow[i] + k0);
      f32x4 a0 = pa[0], a1 = pa[1];
      f32x4 b0 = pb[0], b1 = pb[1];
#pragma unroll
      for (int j = 0; j < 4; ++j) {
        sa[i][j]     = (short)cvt1(a0[j]);
        sa[i][4 + j] = (short)cvt1(a1[j]);
        sb[i][j]     = (short)cvt1(b0[j]);
        sb[i][4 + j] = (short)cvt1(b1[j]);
      }
    }
    __syncthreads();     // all waves done reading previous tile
#pragma unroll
    for (int i = 0; i < 4; ++i) {
      *(short8*)&As[lofs[i]] = sa[i];
      *(short8*)&Bs[lofs[i]] = sb[i];
    }
    __syncthreads();     // tile staged

    // -- fragment reads (swizzled) + MFMA, two K=32 sub-blocks -------------
#pragma unroll
    for (int kk = 0; kk < 2; ++kk) {
      short8 af[4], bfv[4];
#pragma unroll
      for (int mi = 0; mi < 4; ++mi) {
        int row = wm + mi * 16 + lr;
        af[mi] = *(const short8*)&As[row * BK + (((hk + kk * 4) ^ (row & 7)) << 3)];
      }
#pragma unroll
      for (int ni = 0; ni < 4; ++ni) {
        int row = wn + ni * 16 + lr;
        bfv[ni] = *(const short8*)&Bs[row * BK + (((hk + kk * 4) ^ (row & 7)) << 3)];
      }
#pragma unroll
      for (int mi = 0; mi < 4; ++mi)
#pragma unroll
        for (int ni = 0; ni < 4; ++ni)
          acc[mi][ni] = __builtin_amdgcn_mfma_f32_16x16x32_bf16(
              af[mi], bfv[ni], acc[mi][ni], 0, 0, 0);
    }
  }
  __syncthreads();   // all ds_reads consumed -> safe to alias smem as Cs

  // ---- Epilogue 1: repack C (col=lane&15, row=(lane>>4)*4+reg) into Cs ----
  u16* Cs = smem;    // 128*128 u16 = 32 KB, aliases As/Bs
#pragma unroll
  for (int mi = 0; mi < 4; ++mi)
#pragma unroll
    for (int ni = 0; ni < 4; ++ni)
#pragma unroll
      for (int r = 0; r < 4; ++r) {
        int row = wm + mi * 16 + (lane >> 4) * 4 + r;
        int col = wn + ni * 16 + lr;
        Cs[row * BN + col] = f2bf(acc[mi][ni][r]);
      }
  __syncthreads();

  // ---- Epilogue 2: gate-combine complete pairs, plain fp32 stores --------
  const int s0     = rs + (rs & 1);        // first even slot in tile
  const int npairs = (re > s0) ? ((re - s0) >> 1) : 0;
  for (int it = t; it < npairs * 16; it += 256) {
    int p  = it >> 4;
    int cc = (it & 15) * 8;
    int lr0 = (s0 - rs) + 2 * p;           // local row of even slot
    float ga = gates[s0 + 2 * p];
    float gb = gates[s0 + 2 * p + 1];
    short8 c0 = *(const short8*)&Cs[lr0 * BN + cc];
    short8 c1 = *(const short8*)&Cs[(lr0 + 1) * BN + cc];
    f32x4 o0, o1;
#pragma unroll
    for (int j = 0; j < 4; ++j) {
      o0[j] = ga * bf2f((u16)c0[j])     + gb * bf2f((u16)c1[j]);
      o1[j] = ga * bf2f((u16)c0[4 + j]) + gb * bf2f((u16)c1[4 + j]);
    }
    float* dst = out + (size_t)((s0 + 2 * p) >> 1) * OUT_DIM + n0 + cc;
    *(f32x4*)dst       = o0;
    *((f32x4*)dst + 1) = o1;
  }

  // ---- Epilogue 3: edge rows (partner slot outside tile) -> atomicAdd ----
  if (rs & 1) {            // local row 0 = slot rs (odd), token rs>>1
    float g = gates[rs];
    float* dst = out + (size_t)(rs >> 1) * OUT_DIM + n0;
    for (int c = t; c < BN; c += 256)
      atomicAdd(dst + c, g * bf2f(Cs[c]));
  }
  if (re & 1) {            // last row = slot re-1 (even), partner re outside
    int lrow = re - 1 - rs;
    float g = gates[re - 1];
    float* dst = out + (size_t)((re - 1) >> 1) * OUT_DIM + n0;
    for (int c = t; c < BN; c += 256)
      atomicAdd(dst + c, g * bf2f(Cs[lrow * BN + c]));
  }
}

// ---------------------------------------------------------------------------
extern "C" void kernel_launch(void* const* d_in, const int* in_sizes, int n_in,
                              void* d_out, int out_size, void* d_ws, size_t ws_size,
                              hipStream_t stream) {
  const float* X     = (const float*)d_in[0];
  const float* W     = (const float*)d_in[1];
  const float* gates = (const float*)d_in[2];
  const int*   kptr  = (const int*)d_in[3];
  // d_in[4] = sorted_expert_idxs (unused; experts derived from offsets)
  const int*   ssi   = (const int*)d_in[5];
  const int*   eoff  = (const int*)d_in[6];
  float* out = (float*)d_out;

  // tiny ordering dispatch: pre-zero straddle token rows
  hipLaunchKernelGGL(zero_straddle, dim3(MAX_TILES), dim3(256), 0, stream,
                     eoff, out);
  // fused convert+GEMM+combine
  hipLaunchKernelGGL(moe_gemm_fused, dim3(MAX_TILES, NGROUPS), dim3(256),
                     0, stream, X, W, gates, kptr, ssi, eoff, out);
}

// Round 3
// 248.956 us; speedup vs baseline: 1.1847x; 1.1847x over previous
//
#include <hip/hip_runtime.h>
#include <stdint.h>

#define N_EXPERTS 8
#define IN_DIM    1024
#define OUT_DIM   1024
#define N_TOKENS  16384
#define S_SLOTS   (N_TOKENS * 2)
#define BM 128
#define BN 128
#define BK 64                      // bf16 K-cols per LDS tile step
#define MAX_TILES 264              // sum ceil(cnt_e/128) <= 256 + 8
#define NGROUPS   (OUT_DIM / BN)   // 8
#define NXCD      8
#define CPX       (MAX_TILES / NXCD)   // 33 exact -> bijective XCD swizzle

typedef unsigned short u16;
using short4v = __attribute__((ext_vector_type(4))) short;
using short8  = __attribute__((ext_vector_type(8))) short;
using f32x4   = __attribute__((ext_vector_type(4))) float;

__device__ __forceinline__ u16 f2bf(float f) {
  uint32_t x = __builtin_bit_cast(uint32_t, f);
  uint32_t r = x + 0x7fffu + ((x >> 16) & 1u);   // round-to-nearest-even
  return (u16)(r >> 16);
}
__device__ __forceinline__ float bf2f(u16 u) {
  uint32_t x = ((uint32_t)u) << 16;
  return __builtin_bit_cast(float, x);
}

#define GLD_LDS16(g, l) __builtin_amdgcn_global_load_lds(            \
    (const __attribute__((address_space(1))) void*)(g),              \
    (__attribute__((address_space(3))) void*)(l), 16, 0, 0)

// ---------------------------------------------------------------------------
// Shared tile derivation (slots sorted by expert; <=264 M-tiles)
// ---------------------------------------------------------------------------
__device__ __forceinline__ bool derive_tile(const int* eoff_raw, bool is64,
                                            int bx, int& expert, int& rs, int& re) {
  int rem = bx, prev = 0;
  expert = -1;
  for (int e = 0; e < N_EXPERTS; ++e) {
    int end = is64 ? eoff_raw[2 * e] : eoff_raw[e];
    int cnt = end - prev;
    int nt  = (cnt + BM - 1) / BM;
    if (expert < 0) {
      if (rem < nt) {
        expert = e;
        rs = prev + rem * BM;
        re = (rs + BM < end) ? (rs + BM) : end;
      } else {
        rem -= nt;
      }
    }
    prev = end;
  }
  return expert >= 0;
}

// ---------------------------------------------------------------------------
// Node 1: fp32->bf16 convert of X and W, PLUS zeroing of straddle-pair token
// rows (odd tile starts) so the GEMM can atomicAdd edge contributions.
// (Round-0 proven; ~30 us, near streaming roofline.)
// ---------------------------------------------------------------------------
__global__ __launch_bounds__(256) void convert_zero(
    const float* __restrict__ X, const float* __restrict__ W,
    u16* __restrict__ Xb, u16* __restrict__ Wb,
    const int* __restrict__ eoff_raw,
    float* __restrict__ out,
    int xblocks, int wblocks, int xn8, int wn8) {
  int bx = blockIdx.x;
  if (bx < xblocks + wblocks) {
    const float* src; u16* dst; int i, n8;
    if (bx < xblocks) { i = bx * 256 + threadIdx.x; src = X; dst = Xb; n8 = xn8; }
    else { i = (bx - xblocks) * 256 + threadIdx.x; src = W; dst = Wb; n8 = wn8; }
    if (i >= n8) return;
    const f32x4* s = (const f32x4*)src + (size_t)i * 2;
    f32x4 v0 = s[0], v1 = s[1];
    short8 o;
#pragma unroll
    for (int j = 0; j < 4; ++j) {
      o[j]     = (short)f2bf(v0[j]);
      o[4 + j] = (short)f2bf(v1[j]);
    }
    *(short8*)(dst + (size_t)i * 8) = o;
  } else {
    // straddle-row zeroing: tile start rs odd -> pair (rs-1, rs) straddles
    // tiles -> token rs>>1 gets both contributions via atomicAdd.
    int bx2 = bx - xblocks - wblocks;
    const bool is64 = (eoff_raw[7] != S_SLOTS);
    int expert, rs, re;
    if (!derive_tile(eoff_raw, is64, bx2, expert, rs, re)) return;
    if (rs & 1) {
      f32x4 z = (f32x4){0.f, 0.f, 0.f, 0.f};
      *(f32x4*)(out + (size_t)(rs >> 1) * OUT_DIM + threadIdx.x * 4) = z;
    }
  }
}

// ---------------------------------------------------------------------------
// Node 2: grouped GEMM, bf16 workspace inputs, global_load_lds staging.
// BK=64; LDS stays LINEAR (gload_lds requirement) and the bank-conflict
// swizzle is realized by pre-swizzling the per-lane GLOBAL source address
// (rule 21 / m173): physical 16B slot cphys of row holds logical chunk
// cphys ^ (row&7).  ds_read_b128 fragment loads use the same XOR -> 2
// lanes/bank (free, m136) instead of the old 8-way conflict.
// XCD-aware bijective tile swizzle for W-panel L2 locality.
// Epilogue: proven repack + gate-combine pairs + atomicAdd edges.
// ---------------------------------------------------------------------------
__global__ __launch_bounds__(256) void moe_gemm_out(
    const u16*   __restrict__ Xb,       // [N_TOKENS, IN_DIM] bf16 (ws)
    const u16*   __restrict__ Wb,       // [E, OUT_DIM, IN_DIM] bf16 (ws)
    const float* __restrict__ gates,    // [S] fp32
    const int*   __restrict__ kptr,
    const int*   __restrict__ ssi_raw,  // int32 or int64
    const int*   __restrict__ eoff_raw, // int32 or int64
    float*       __restrict__ out)      // [N_TOKENS, OUT_DIM] fp32
{
  __shared__ __align__(16) u16 smem[BM * BK + BN * BK];   // 32 KB
  u16* As = smem;             // [128 rows][8 slots of 16B], slots XOR-placed
  u16* Bs = smem + BM * BK;

  const bool is64 = (eoff_raw[7] != S_SLOTS);
  const int tile = (blockIdx.x % NXCD) * CPX + blockIdx.x / NXCD;
  int expert, rs, re;
  if (!derive_tile(eoff_raw, is64, tile, expert, rs, re)) return;

  const int n0   = blockIdx.y * BN;
  const int kdiv = kptr[0];
  const int t    = threadIdx.x;

  // staging: 1024 16B-chunks per operand; thread t handles q = t + 256*i.
  // LDS placement is linear in q; global source picks the XOR-swizzled
  // logical chunk so the LDS ends up swizzled "for free".
  const u16* asrc[4];
  const u16* bsrc[4];
#pragma unroll
  for (int i = 0; i < 4; ++i) {
    int q = t + 256 * i;
    int row = q >> 3, cphys = q & 7;
    int clog = cphys ^ (row & 7);
    int g = rs + row; if (g >= re) g = re - 1;
    int sv  = is64 ? ssi_raw[2 * g] : ssi_raw[g];
    int tok = sv / kdiv;
    asrc[i] = Xb + (size_t)tok * IN_DIM + clog * 8;
    bsrc[i] = Wb + ((size_t)expert * OUT_DIM + n0 + row) * IN_DIM + clog * 8;
  }

  f32x4 acc[4][4];
#pragma unroll
  for (int i = 0; i < 4; ++i)
#pragma unroll
    for (int j = 0; j < 4; ++j)
      acc[i][j] = (f32x4){0.f, 0.f, 0.f, 0.f};

  const int wave = t >> 6;
  const int lane = t & 63;
  const int wm = (wave >> 1) * 64;
  const int wn = (wave & 1) * 64;
  const int lr = lane & 15;
  const int hk = lane >> 4;          // k-chunk selector within a K=32 block

  for (int k0 = 0; k0 < IN_DIM; k0 += BK) {
#pragma unroll
    for (int i = 0; i < 4; ++i) {
      GLD_LDS16(asrc[i] + k0, As + (size_t)(t + 256 * i) * 8);
      GLD_LDS16(bsrc[i] + k0, Bs + (size_t)(t + 256 * i) * 8);
    }
    __syncthreads();   // drains vmcnt -> LDS tile valid

#pragma unroll
    for (int kk = 0; kk < 2; ++kk) {
      short8 af[4], bfv[4];
#pragma unroll
      for (int mi = 0; mi < 4; ++mi) {
        int row = wm + mi * 16 + lr;
        af[mi] = *(const short8*)&As[row * BK + (((kk * 4 + hk) ^ (row & 7)) << 3)];
      }
#pragma unroll
      for (int ni = 0; ni < 4; ++ni) {
        int row = wn + ni * 16 + lr;
        bfv[ni] = *(const short8*)&Bs[row * BK + (((kk * 4 + hk) ^ (row & 7)) << 3)];
      }
#pragma unroll
      for (int mi = 0; mi < 4; ++mi)
#pragma unroll
        for (int ni = 0; ni < 4; ++ni)
          acc[mi][ni] = __builtin_amdgcn_mfma_f32_16x16x32_bf16(
              af[mi], bfv[ni], acc[mi][ni], 0, 0, 0);
    }
    __syncthreads();   // all reads consumed before next tile overwrites
  }

  // ---- Epilogue 1: repack C (col=lane&15, row=(lane>>4)*4+reg) into Cs ----
  u16* Cs = smem;   // aliases As/Bs (trailing barrier above makes this safe)
#pragma unroll
  for (int mi = 0; mi < 4; ++mi)
#pragma unroll
    for (int ni = 0; ni < 4; ++ni)
#pragma unroll
      for (int r = 0; r < 4; ++r) {
        int row = wm + mi * 16 + (lane >> 4) * 4 + r;
        int col = wn + ni * 16 + lr;
        Cs[row * BN + col] = f2bf(acc[mi][ni][r]);
      }
  __syncthreads();

  // ---- Epilogue 2: gate-combine complete pairs, plain fp32 stores --------
  const int s0     = rs + (rs & 1);        // first even slot in tile
  const int npairs = (re > s0) ? ((re - s0) >> 1) : 0;
  for (int it = t; it < npairs * 16; it += 256) {
    int p  = it >> 4;
    int cc = (it & 15) * 8;
    int lr0 = (s0 - rs) + 2 * p;           // local row of even slot
    float ga = gates[s0 + 2 * p];
    float gb = gates[s0 + 2 * p + 1];
    short8 c0 = *(const short8*)&Cs[lr0 * BN + cc];
    short8 c1 = *(const short8*)&Cs[(lr0 + 1) * BN + cc];
    f32x4 o0, o1;
#pragma unroll
    for (int j = 0; j < 4; ++j) {
      o0[j] = ga * bf2f((u16)c0[j])     + gb * bf2f((u16)c1[j]);
      o1[j] = ga * bf2f((u16)c0[4 + j]) + gb * bf2f((u16)c1[4 + j]);
    }
    float* dst = out + (size_t)((s0 + 2 * p) >> 1) * OUT_DIM + n0 + cc;
    *(f32x4*)dst       = o0;
    *((f32x4*)dst + 1) = o1;
  }

  // ---- Epilogue 3: edge rows (partner slot outside tile) -> atomicAdd ----
  if (rs & 1) {            // local row 0 = slot rs (odd), token rs>>1
    float g = gates[rs];
    float* dst = out + (size_t)(rs >> 1) * OUT_DIM + n0;
    for (int c = t; c < BN; c += 256)
      atomicAdd(dst + c, g * bf2f(Cs[c]));
  }
  if (re & 1) {            // last row = slot re-1 (even), partner re outside
    int lrow = re - 1 - rs;
    float g = gates[re - 1];
    float* dst = out + (size_t)((re - 1) >> 1) * OUT_DIM + n0;
    for (int c = t; c < BN; c += 256)
      atomicAdd(dst + c, g * bf2f(Cs[lrow * BN + c]));
  }
}

// ---------------------------------------------------------------------------
// Last-resort fallback (verified in an earlier session): fp32 staging +
// inline convert + atomics.  Only used if the workspace is too small.
// ---------------------------------------------------------------------------
__global__ __launch_bounds__(256) void moe_gemm_fused_f32(
    const float* __restrict__ X, const float* __restrict__ W,
    const float* __restrict__ gates, const int* __restrict__ kptr,
    const int*   __restrict__ ssi_raw, const int* __restrict__ eoff_raw,
    float*       __restrict__ out)
{
  __shared__ __align__(16) u16 As[BM * 32];
  __shared__ __align__(16) u16 Bs[BN * 32];

  const bool is64 = (eoff_raw[7] != S_SLOTS);
  int expert, rs, re;
  if (!derive_tile(eoff_raw, is64, blockIdx.x, expert, rs, re)) return;
  const int rcount = re - rs;

  const int n0   = blockIdx.y * BN;
  const int kdiv = kptr[0];
  const int t    = threadIdx.x;

  const float* arow[4];
  const float* brow[4];
  int lofs[4];
#pragma unroll
  for (int i = 0; i < 4; ++i) {
    int c = t + 256 * i;
    int r = c >> 3;
    int col4 = (c & 7) * 4;
    int g = rs + r; if (g >= re) g = re - 1;
    int sval = is64 ? ssi_raw[2 * g] : ssi_raw[g];
    int tok  = sval / kdiv;
    arow[i] = X + (size_t)tok * IN_DIM + col4;
    brow[i] = W + ((size_t)expert * OUT_DIM + n0 + r) * IN_DIM + col4;
    lofs[i] = r * 32 + col4;
  }

  f32x4 acc[4][4];
#pragma unroll
  for (int i = 0; i < 4; ++i)
#pragma unroll
    for (int j = 0; j < 4; ++j)
      acc[i][j] = (f32x4){0.f, 0.f, 0.f, 0.f};

  const int wave = t >> 6;
  const int lane = t & 63;
  const int wm = (wave >> 1) * 64;
  const int wn = (wave & 1) * 64;
  const int lr = lane & 15;
  const int lk = (lane >> 4) * 8;

  for (int k0 = 0; k0 < IN_DIM; k0 += 32) {
    f32x4 a[4], b[4];
#pragma unroll
    for (int i = 0; i < 4; ++i) {
      a[i] = *(const f32x4*)(arow[i] + k0);
      b[i] = *(const f32x4*)(brow[i] + k0);
    }
    __syncthreads();
#pragma unroll
    for (int i = 0; i < 4; ++i) {
      short4v av, bv;
#pragma unroll
      for (int j = 0; j < 4; ++j) {
        av[j] = (short)f2bf(a[i][j]);
        bv[j] = (short)f2bf(b[i][j]);
      }
      *(short4v*)&As[lofs[i]] = av;
      *(short4v*)&Bs[lofs[i]] = bv;
    }
    __syncthreads();

    short8 af[4], bfv[4];
#pragma unroll
    for (int mi = 0; mi < 4; ++mi)
      af[mi] = *(const short8*)&As[(wm + mi * 16 + lr) * 32 + lk];
#pragma unroll
    for (int ni = 0; ni < 4; ++ni)
      bfv[ni] = *(const short8*)&Bs[(wn + ni * 16 + lr) * 32 + lk];

#pragma unroll
    for (int mi = 0; mi < 4; ++mi)
#pragma unroll
      for (int ni = 0; ni < 4; ++ni)
        acc[mi][ni] = __builtin_amdgcn_mfma_f32_16x16x32_bf16(
            af[mi], bfv[ni], acc[mi][ni], 0, 0, 0);
  }

#pragma unroll
  for (int mi = 0; mi < 4; ++mi) {
#pragma unroll
    for (int r = 0; r < 4; ++r) {
      int row = wm + mi * 16 + (lane >> 4) * 4 + r;
      if (row < rcount) {
        int slot  = rs + row;
        int token = slot / kdiv;
        float g   = gates[slot];
        float* dst = out + (size_t)token * OUT_DIM + n0;
#pragma unroll
        for (int ni = 0; ni < 4; ++ni) {
          int col = wn + ni * 16 + lr;
          atomicAdd(dst + col, g * acc[mi][ni][r]);
        }
      }
    }
  }
}

// ---------------------------------------------------------------------------
extern "C" void kernel_launch(void* const* d_in, const int* in_sizes, int n_in,
                              void* d_out, int out_size, void* d_ws, size_t ws_size,
                              hipStream_t stream) {
  const float* X     = (const float*)d_in[0];
  const float* W     = (const float*)d_in[1];
  const float* gates = (const float*)d_in[2];
  const int*   kptr  = (const int*)d_in[3];
  // d_in[4] = sorted_expert_idxs (unused; experts derived from offsets)
  const int*   ssi   = (const int*)d_in[5];
  const int*   eoff  = (const int*)d_in[6];
  float* out = (float*)d_out;

  const size_t x_elems = (size_t)N_TOKENS * IN_DIM;            // 16.7M
  const size_t w_elems = (size_t)N_EXPERTS * OUT_DIM * IN_DIM; // 8.4M
  const size_t need = (x_elems + w_elems) * sizeof(u16);       // 50 MB

  if (ws_size >= need) {
    u16* Xb = (u16*)d_ws;
    u16* Wb = Xb + x_elems;
    const int xn8 = (int)(x_elems / 8), wn8 = (int)(w_elems / 8);
    const int xblocks = (xn8 + 255) / 256, wblocks = (wn8 + 255) / 256;
    hipLaunchKernelGGL(convert_zero, dim3(xblocks + wblocks + MAX_TILES),
                       dim3(256), 0, stream, X, W, Xb, Wb, eoff, out,
                       xblocks, wblocks, xn8, wn8);
    hipLaunchKernelGGL(moe_gemm_out, dim3(MAX_TILES, NGROUPS), dim3(256),
                       0, stream, Xb, Wb, gates, kptr, ssi, eoff, out);
  } else {
    hipMemsetAsync(d_out, 0, (size_t)out_size * sizeof(float), stream);
    hipLaunchKernelGGL(moe_gemm_fused_f32, dim3(MAX_TILES, NGROUPS), dim3(256),
                       0, stream, X, W, gates, kptr, ssi, eoff, out);
  }
}

// Round 4
// 247.997 us; speedup vs baseline: 1.1893x; 1.0039x over previous
//
#include <hip/hip_runtime.h>
#include <stdint.h>

#define N_EXPERTS 8
#define IN_DIM    1024
#define OUT_DIM   1024
#define N_TOKENS  16384
#define S_SLOTS   (N_TOKENS * 2)

// ---- main 256x256 phase-split GEMM geometry ----
#define BM   256
#define BN   256
#define BK   64                    // bf16 K-cols per LDS tile step
#define NKT  (IN_DIM / BK)         // 16 K-tiles
#define MT   136                   // sum ceil(cnt_e/256) <= 128 + 8
#define NG   (OUT_DIM / BN)        // 4
#define NXCD 8
#define CPX  (MT / NXCD)           // 17 exact -> bijective XCD swizzle

// ---- fallback geometry (verified legacy path) ----
#define FBM  128
#define FMT  264

typedef unsigned short u16;
using short4v = __attribute__((ext_vector_type(4))) short;
using short8  = __attribute__((ext_vector_type(8))) short;
using f32x4   = __attribute__((ext_vector_type(4))) float;

__device__ __forceinline__ u16 f2bf(float f) {
  uint32_t x = __builtin_bit_cast(uint32_t, f);
  uint32_t r = x + 0x7fffu + ((x >> 16) & 1u);   // round-to-nearest-even
  return (u16)(r >> 16);
}
__device__ __forceinline__ float bf2f(u16 u) {
  uint32_t x = ((uint32_t)u) << 16;
  return __builtin_bit_cast(float, x);
}

#define GLD_LDS16(g, l) __builtin_amdgcn_global_load_lds(            \
    (const __attribute__((address_space(1))) void*)(g),              \
    (__attribute__((address_space(3))) void*)(l), 16, 0, 0)

// ---------------------------------------------------------------------------
// Shared tile derivation (slots sorted by expert), parametric block-M.
// ---------------------------------------------------------------------------
__device__ __forceinline__ bool derive_tile(const int* eoff_raw, bool is64,
                                            int bx, int bm,
                                            int& expert, int& rs, int& re) {
  int rem = bx, prev = 0;
  expert = -1;
  for (int e = 0; e < N_EXPERTS; ++e) {
    int end = is64 ? eoff_raw[2 * e] : eoff_raw[e];
    int cnt = end - prev;
    int nt  = (cnt + bm - 1) / bm;
    if (expert < 0) {
      if (rem < nt) {
        expert = e;
        rs = prev + rem * bm;
        re = (rs + bm < end) ? (rs + bm) : end;
      } else {
        rem -= nt;
      }
    }
    prev = end;
  }
  return expert >= 0;
}

// ---------------------------------------------------------------------------
// Node 1: fp32->bf16 convert of X and W, PLUS zeroing of straddle-pair token
// rows (odd 256-tile starts) so the GEMM can atomicAdd edge contributions.
// ---------------------------------------------------------------------------
__global__ __launch_bounds__(256) void convert_zero(
    const float* __restrict__ X, const float* __restrict__ W,
    u16* __restrict__ Xb, u16* __restrict__ Wb,
    const int* __restrict__ eoff_raw,
    float* __restrict__ out,
    int xblocks, int wblocks, int xn8, int wn8) {
  int bx = blockIdx.x;
  if (bx < xblocks + wblocks) {
    const float* src; u16* dst; int i, n8;
    if (bx < xblocks) { i = bx * 256 + threadIdx.x; src = X; dst = Xb; n8 = xn8; }
    else { i = (bx - xblocks) * 256 + threadIdx.x; src = W; dst = Wb; n8 = wn8; }
    if (i >= n8) return;
    const f32x4* s = (const f32x4*)src + (size_t)i * 2;
    f32x4 v0 = s[0], v1 = s[1];
    short8 o;
#pragma unroll
    for (int j = 0; j < 4; ++j) {
      o[j]     = (short)f2bf(v0[j]);
      o[4 + j] = (short)f2bf(v1[j]);
    }
    *(short8*)(dst + (size_t)i * 8) = o;
  } else {
    int bx2 = bx - xblocks - wblocks;
    const bool is64 = (eoff_raw[7] != S_SLOTS);
    int expert, rs, re;
    if (!derive_tile(eoff_raw, is64, bx2, BM, expert, rs, re)) return;
    if (rs & 1) {
      f32x4 z = (f32x4){0.f, 0.f, 0.f, 0.f};
      *(f32x4*)(out + (size_t)(rs >> 1) * OUT_DIM + threadIdx.x * 4) = z;
    }
  }
}

// ---------------------------------------------------------------------------
// Node 2: 256x256 grouped GEMM, phase-split schedule (T3+T4+T5 port):
//  - double-buffered LDS K-tiles (A/B, 128 KB), staged via global_load_lds
//    with source-pre-swizzled addresses (linear LDS dest, rule 21/m173)
//  - 4 phases per K-tile: {issue 2 prefetch loads || ds_read frag subtile}
//    -> s_barrier -> lgkmcnt(0)+sched_barrier -> setprio(1) -> 16 MFMA ->
//    setprio(0) -> s_barrier.  Raw barriers: prefetch vmcnt survives them;
//    vmcnt(0) only once per K-tile at the buffer swap.
//  - 8 waves (2M x 4N), per-wave 128x64 output, acc = 8x4 f32x4.
// Epilogue: proven LDS repack + gate-combine pairs + atomicAdd edges.
// ---------------------------------------------------------------------------
__global__ __launch_bounds__(512, 2) void moe_gemm_256(
    const u16*   __restrict__ Xb,       // [N_TOKENS, IN_DIM] bf16 (ws)
    const u16*   __restrict__ Wb,       // [E, OUT_DIM, IN_DIM] bf16 (ws)
    const float* __restrict__ gates,    // [S] fp32
    const int*   __restrict__ kptr,
    const int*   __restrict__ ssi_raw,  // int32 or int64
    const int*   __restrict__ eoff_raw, // int32 or int64
    float*       __restrict__ out)      // [N_TOKENS, OUT_DIM] fp32
{
  // staging: A0 [0,16384) A1 [16384,32768) B0 [32768,49152) B1 [49152,65536)
  // (u16 units; each buffer 256 rows x 64 cols = 32 KB). Epilogue aliases
  // the whole 128 KB as Cs[256][256] bf16.
  __shared__ __align__(16) u16 smem[BM * BN];

  const bool is64 = (eoff_raw[7] != S_SLOTS);
  const int tile = (blockIdx.x % NXCD) * CPX + blockIdx.x / NXCD;
  int expert, rs, re;
  if (!derive_tile(eoff_raw, is64, tile, BM, expert, rs, re)) return;

  const int n0   = blockIdx.y * BN;
  const int kdiv = kptr[0];
  const int t    = threadIdx.x;

  // --- staging sources: chunk q = t + 512*j -> row q>>3, phys slot q&7.
  // Physical slot holds logical chunk (q&7)^(row&7) -> LDS ends up swizzled
  // while the gload_lds destination stays linear (wave-uniform + lane*16B).
  const u16* asrc[4];
  const u16* bsrc[4];
#pragma unroll
  for (int j = 0; j < 4; ++j) {
    int q = t + 512 * j;
    int row = q >> 3, cphys = q & 7;
    int clog = cphys ^ (row & 7);
    int g = rs + row; if (g >= re) g = re - 1;
    int sv  = is64 ? ssi_raw[2 * g] : ssi_raw[g];
    int tok = sv / kdiv;
    asrc[j] = Xb + (size_t)tok * IN_DIM + clog * 8;
    bsrc[j] = Wb + ((size_t)expert * OUT_DIM + n0 + row) * IN_DIM + clog * 8;
  }

  f32x4 acc[8][4];
#pragma unroll
  for (int i = 0; i < 8; ++i)
#pragma unroll
    for (int j = 0; j < 4; ++j)
      acc[i][j] = (f32x4){0.f, 0.f, 0.f, 0.f};

  const int wave = t >> 6;
  const int lane = t & 63;
  const int wm = (wave >> 2) * 128;      // 2 M-wave rows
  const int wn = (wave & 3) * 64;        // 4 N-wave cols
  const int lr = lane & 15;
  const int hk = lane >> 4;
  // swizzled chunk byte-offsets (lane-constant since row&7 == lr&7)
  const int ck0 = ((hk    ) ^ (lr & 7)) << 3;   // kk=0, u16 offset
  const int ck1 = ((hk + 4) ^ (lr & 7)) << 3;   // kk=1

  // ---- prologue: stage K-tile 0 into buffer 0, full drain ----
#pragma unroll
  for (int j = 0; j < 4; ++j) {
    GLD_LDS16(asrc[j],          smem +         (size_t)(t + 512 * j) * 8);
    GLD_LDS16(bsrc[j], smem + 32768 + (size_t)(t + 512 * j) * 8);
  }
  asm volatile("s_waitcnt vmcnt(0)" ::: "memory");
  __builtin_amdgcn_s_barrier();
  __builtin_amdgcn_sched_barrier(0);

  for (int kt = 0; kt < NKT; ++kt) {
    const int cb = kt & 1, nb = cb ^ 1;
    u16* const Ac = smem + cb * 16384;
    u16* const Bc = smem + 32768 + cb * 16384;
    u16* const An = smem + nb * 16384;
    u16* const Bn = smem + 32768 + nb * 16384;
    const int  kn  = (kt + 1) * BK;       // next-tile K offset (u16 elems)
    const bool pre = (kt + 1 < NKT);

    short8 bfr[4][2];                     // B-frags persist across phases
#pragma unroll
    for (int p = 0; p < 4; ++p) {
      // --- issue 2 prefetch loads of the NEXT K-tile (survive barriers) ---
      if (pre) {
        if (p < 2) {
          GLD_LDS16(asrc[2 * p]     + kn, An + (size_t)(t + 512 * (2 * p)) * 8);
          GLD_LDS16(asrc[2 * p + 1] + kn, An + (size_t)(t + 512 * (2 * p + 1)) * 8);
        } else {
          GLD_LDS16(bsrc[2 * (p - 2)]     + kn, Bn + (size_t)(t + 512 * (2 * (p - 2))) * 8);
          GLD_LDS16(bsrc[2 * (p - 2) + 1] + kn, Bn + (size_t)(t + 512 * (2 * (p - 2) + 1)) * 8);
        }
      }
      // --- frag ds_reads for this phase (swizzled, conflict-free) ---
      if (p == 0) {
#pragma unroll
        for (int ni = 0; ni < 4; ++ni) {
          const u16* rb = Bc + (size_t)(wn + ni * 16 + lr) * BK;
          bfr[ni][0] = *(const short8*)(rb + ck0);
          bfr[ni][1] = *(const short8*)(rb + ck1);
        }
      }
      short8 af[2][2];
#pragma unroll
      for (int m2 = 0; m2 < 2; ++m2) {
        const u16* ra = Ac + (size_t)(wm + (2 * p + m2) * 16 + lr) * BK;
        af[m2][0] = *(const short8*)(ra + ck0);
        af[m2][1] = *(const short8*)(ra + ck1);
      }
      __builtin_amdgcn_s_barrier();                       // phase gate
      asm volatile("s_waitcnt lgkmcnt(0)" ::: "memory");  // frags landed
      __builtin_amdgcn_sched_barrier(0);                  // rule 18
      __builtin_amdgcn_s_setprio(1);
#pragma unroll
      for (int m2 = 0; m2 < 2; ++m2)
#pragma unroll
        for (int ni = 0; ni < 4; ++ni) {
          acc[2 * p + m2][ni] = __builtin_amdgcn_mfma_f32_16x16x32_bf16(
              af[m2][0], bfr[ni][0], acc[2 * p + m2][ni], 0, 0, 0);
          acc[2 * p + m2][ni] = __builtin_amdgcn_mfma_f32_16x16x32_bf16(
              af[m2][1], bfr[ni][1], acc[2 * p + m2][ni], 0, 0, 0);
        }
      __builtin_amdgcn_s_setprio(0);
      __builtin_amdgcn_s_barrier();                       // phase end
    }
    // ---- K-tile boundary: own prefetch landed, everyone done reading ----
    asm volatile("s_waitcnt vmcnt(0)" ::: "memory");
    __builtin_amdgcn_s_barrier();
    __builtin_amdgcn_sched_barrier(0);
  }

  // ---- Epilogue 1: repack C (col=lane&15, row=(lane>>4)*4+reg) into Cs ----
  u16* Cs = smem;    // aliases staging buffers (boundary barrier above)
#pragma unroll
  for (int mi = 0; mi < 8; ++mi)
#pragma unroll
    for (int ni = 0; ni < 4; ++ni)
#pragma unroll
      for (int r = 0; r < 4; ++r) {
        int row = wm + mi * 16 + (lane >> 4) * 4 + r;
        int col = wn + ni * 16 + lr;
        Cs[row * BN + col] = f2bf(acc[mi][ni][r]);
      }
  __syncthreads();

  // ---- Epilogue 2: gate-combine complete pairs, plain fp32 stores --------
  const int s0     = rs + (rs & 1);        // first even slot in tile
  const int npairs = (re > s0) ? ((re - s0) >> 1) : 0;
  for (int it = t; it < npairs * 32; it += 512) {
    int p  = it >> 5;
    int cc = (it & 31) * 8;
    int lr0 = (s0 - rs) + 2 * p;           // local row of even slot
    float ga = gates[s0 + 2 * p];
    float gb = gates[s0 + 2 * p + 1];
    short8 c0 = *(const short8*)&Cs[lr0 * BN + cc];
    short8 c1 = *(const short8*)&Cs[(lr0 + 1) * BN + cc];
    f32x4 o0, o1;
#pragma unroll
    for (int j = 0; j < 4; ++j) {
      o0[j] = ga * bf2f((u16)c0[j])     + gb * bf2f((u16)c1[j]);
      o1[j] = ga * bf2f((u16)c0[4 + j]) + gb * bf2f((u16)c1[4 + j]);
    }
    float* dst = out + (size_t)((s0 + 2 * p) >> 1) * OUT_DIM + n0 + cc;
    *(f32x4*)dst       = o0;
    *((f32x4*)dst + 1) = o1;
  }

  // ---- Epilogue 3: edge rows (partner slot outside tile) -> atomicAdd ----
  if (rs & 1) {            // local row 0 = slot rs (odd), token rs>>1
    float g = gates[rs];
    float* dst = out + (size_t)(rs >> 1) * OUT_DIM + n0;
    for (int c = t; c < BN; c += 512)
      atomicAdd(dst + c, g * bf2f(Cs[c]));
  }
  if (re & 1) {            // last row = slot re-1 (even), partner re outside
    int lrow = re - 1 - rs;
    float g = gates[re - 1];
    float* dst = out + (size_t)((re - 1) >> 1) * OUT_DIM + n0;
    for (int c = t; c < BN; c += 512)
      atomicAdd(dst + c, g * bf2f(Cs[lrow * BN + c]));
  }
}

// ---------------------------------------------------------------------------
// Last-resort fallback (verified): fp32 staging + inline convert + atomics.
// Only used if the workspace is too small.  128-row tiles, own grid.
// ---------------------------------------------------------------------------
__global__ __launch_bounds__(256) void moe_gemm_fused_f32(
    const float* __restrict__ X, const float* __restrict__ W,
    const float* __restrict__ gates, const int* __restrict__ kptr,
    const int*   __restrict__ ssi_raw, const int* __restrict__ eoff_raw,
    float*       __restrict__ out)
{
  __shared__ __align__(16) u16 As[FBM * 32];
  __shared__ __align__(16) u16 Bs[FBM * 32];

  const bool is64 = (eoff_raw[7] != S_SLOTS);
  int expert, rs, re;
  if (!derive_tile(eoff_raw, is64, blockIdx.x, FBM, expert, rs, re)) return;
  const int rcount = re - rs;

  const int n0   = blockIdx.y * 128;
  const int kdiv = kptr[0];
  const int t    = threadIdx.x;

  const float* arow[4];
  const float* brow[4];
  int lofs[4];
#pragma unroll
  for (int i = 0; i < 4; ++i) {
    int c = t + 256 * i;
    int r = c >> 3;
    int col4 = (c & 7) * 4;
    int g = rs + r; if (g >= re) g = re - 1;
    int sval = is64 ? ssi_raw[2 * g] : ssi_raw[g];
    int tok  = sval / kdiv;
    arow[i] = X + (size_t)tok * IN_DIM + col4;
    brow[i] = W + ((size_t)expert * OUT_DIM + n0 + r) * IN_DIM + col4;
    lofs[i] = r * 32 + col4;
  }

  f32x4 acc[4][4];
#pragma unroll
  for (int i = 0; i < 4; ++i)
#pragma unroll
    for (int j = 0; j < 4; ++j)
      acc[i][j] = (f32x4){0.f, 0.f, 0.f, 0.f};

  const int wave = t >> 6;
  const int lane = t & 63;
  const int wm = (wave >> 1) * 64;
  const int wn = (wave & 1) * 64;
  const int lr = lane & 15;
  const int lk = (lane >> 4) * 8;

  for (int k0 = 0; k0 < IN_DIM; k0 += 32) {
    f32x4 a[4], b[4];
#pragma unroll
    for (int i = 0; i < 4; ++i) {
      a[i] = *(const f32x4*)(arow[i] + k0);
      b[i] = *(const f32x4*)(brow[i] + k0);
    }
    __syncthreads();
#pragma unroll
    for (int i = 0; i < 4; ++i) {
      short4v av, bv;
#pragma unroll
      for (int j = 0; j < 4; ++j) {
        av[j] = (short)f2bf(a[i][j]);
        bv[j] = (short)f2bf(b[i][j]);
      }
      *(short4v*)&As[lofs[i]] = av;
      *(short4v*)&Bs[lofs[i]] = bv;
    }
    __syncthreads();

    short8 af[4], bfv[4];
#pragma unroll
    for (int mi = 0; mi < 4; ++mi)
      af[mi] = *(const short8*)&As[(wm + mi * 16 + lr) * 32 + lk];
#pragma unroll
    for (int ni = 0; ni < 4; ++ni)
      bfv[ni] = *(const short8*)&Bs[(wn + ni * 16 + lr) * 32 + lk];

#pragma unroll
    for (int mi = 0; mi < 4; ++mi)
#pragma unroll
      for (int ni = 0; ni < 4; ++ni)
        acc[mi][ni] = __builtin_amdgcn_mfma_f32_16x16x32_bf16(
            af[mi], bfv[ni], acc[mi][ni], 0, 0, 0);
  }

#pragma unroll
  for (int mi = 0; mi < 4; ++mi) {
#pragma unroll
    for (int r = 0; r < 4; ++r) {
      int row = wm + mi * 16 + (lane >> 4) * 4 + r;
      if (row < rcount) {
        int slot  = rs + row;
        int token = slot / kdiv;
        float g   = gates[slot];
        float* dst = out + (size_t)token * OUT_DIM + n0;
#pragma unroll
        for (int ni = 0; ni < 4; ++ni) {
          int col = wn + ni * 16 + lr;
          atomicAdd(dst + col, g * acc[mi][ni][r]);
        }
      }
    }
  }
}

// ---------------------------------------------------------------------------
extern "C" void kernel_launch(void* const* d_in, const int* in_sizes, int n_in,
                              void* d_out, int out_size, void* d_ws, size_t ws_size,
                              hipStream_t stream) {
  const float* X     = (const float*)d_in[0];
  const float* W     = (const float*)d_in[1];
  const float* gates = (const float*)d_in[2];
  const int*   kptr  = (const int*)d_in[3];
  // d_in[4] = sorted_expert_idxs (unused; experts derived from offsets)
  const int*   ssi   = (const int*)d_in[5];
  const int*   eoff  = (const int*)d_in[6];
  float* out = (float*)d_out;

  const size_t x_elems = (size_t)N_TOKENS * IN_DIM;            // 16.7M
  const size_t w_elems = (size_t)N_EXPERTS * OUT_DIM * IN_DIM; // 8.4M
  const size_t need = (x_elems + w_elems) * sizeof(u16);       // 50 MB

  if (ws_size >= need) {
    u16* Xb = (u16*)d_ws;
    u16* Wb = Xb + x_elems;
    const int xn8 = (int)(x_elems / 8), wn8 = (int)(w_elems / 8);
    const int xblocks = (xn8 + 255) / 256, wblocks = (wn8 + 255) / 256;
    hipLaunchKernelGGL(convert_zero, dim3(xblocks + wblocks + MT),
                       dim3(256), 0, stream, X, W, Xb, Wb, eoff, out,
                       xblocks, wblocks, xn8, wn8);
    hipLaunchKernelGGL(moe_gemm_256, dim3(MT, NG), dim3(512),
                       0, stream, Xb, Wb, gates, kptr, ssi, eoff, out);
  } else {
    hipMemsetAsync(d_out, 0, (size_t)out_size * sizeof(float), stream);
    hipLaunchKernelGGL(moe_gemm_fused_f32, dim3(FMT, 8), dim3(256),
                       0, stream, X, W, gates, kptr, ssi, eoff, out);
  }
}